// Round 1
// baseline (185.812 us; speedup 1.0000x reference)
//
#include <hip/hip_runtime.h>

// OptimizedLinear: out = x@W^T + bias - lr[:,None]*(x@G^T + bias_grad)
// B=4096, IN=OUT=2048, fp32 in/out. Strategy: bf16 MFMA (threshold permits),
// fused dual-accumulator GEMM (A-tile staged once, used for both W and G),
// epilogue applies the per-sample lr combine. m97-style structure:
// 128x128 tile, BK=32, global_load_lds width=16, 16x16x32 bf16 MFMA.

typedef unsigned short ushort_t;
typedef __attribute__((ext_vector_type(8))) short short8;       // 8 bf16 = 4 VGPR
typedef __attribute__((ext_vector_type(8))) unsigned short ushort8;
typedef __attribute__((ext_vector_type(4))) float f32x4;

#define GPTR(p) ((const __attribute__((address_space(1))) void*)(p))
#define LPTR(p) ((__attribute__((address_space(3))) void*)(p))

__device__ __forceinline__ unsigned short f2bf(float f) {
    union { float f; unsigned u; } c; c.f = f;
    unsigned u = c.u;
    // round-to-nearest-even
    unsigned r = (u + 0x7fffu + ((u >> 16) & 1u)) >> 16;
    return (unsigned short)r;
}

// fp32 -> bf16 convert, 8 elems/thread, n must be divisible by 8
__global__ void cvt_bf16_kernel(const float* __restrict__ src,
                                ushort_t* __restrict__ dst, int n) {
    int i = (blockIdx.x * blockDim.x + threadIdx.x) * 8;
    if (i >= n) return;
    float4 a = *(const float4*)(src + i);
    float4 b = *(const float4*)(src + i + 4);
    ushort8 r;
    r[0] = f2bf(a.x); r[1] = f2bf(a.y); r[2] = f2bf(a.z); r[3] = f2bf(a.w);
    r[4] = f2bf(b.x); r[5] = f2bf(b.y); r[6] = f2bf(b.z); r[7] = f2bf(b.w);
    *(ushort8*)(dst + i) = r;
}

// ---- fused dual GEMM ----
// C-tile 128x128 per block (grid 16 x 32), 256 threads = 4 waves, each wave
// owns a 64x64 region = 4x4 grid of 16x16 MFMA tiles, dual accumulators.
static constexpr int Kdim = 2048;
static constexpr int Ndim = 2048;

__global__ __launch_bounds__(256, 2) void fused_gemm_kernel(
    const ushort_t* __restrict__ xb,   // [4096, 2048] bf16
    const ushort_t* __restrict__ wb,   // [2048, 2048] bf16 (row = out, col = in -> B^T layout)
    const ushort_t* __restrict__ gb,   // [2048, 2048] bf16
    const float* __restrict__ bias,    // [2048]
    const float* __restrict__ bgrad,   // [2048]
    const float* __restrict__ lr,      // [4096]
    float* __restrict__ out)           // [4096, 2048] fp32
{
    __shared__ ushort_t As[128 * 32];
    __shared__ ushort_t Ws[128 * 32];
    __shared__ ushort_t Gs[128 * 32];

    const int t    = threadIdx.x;
    const int wave = t >> 6;
    const int lane = t & 63;
    const int wm   = (wave >> 1) * 64;   // wave's row offset in 128x128 tile
    const int wn   = (wave & 1) * 64;    // wave's col offset
    const int bx   = blockIdx.x;         // N tile (0..15)
    const int by   = blockIdx.y;         // M tile (0..31)

    f32x4 accB[4][4] = {};  // base = x@W^T
    f32x4 accP[4][4] = {};  // pert = x@G^T

    // --- staging addressing (global_load_lds, width=16 = 8 bf16/lane) ---
    // tile is 128 rows x 32 k, linearized row-major (k contiguous, 64B/row).
    // issue i, thread t covers elems [(i*256+t)*8 .. +8): row=(i*256+t)/4, k=((i*256+t)%4)*8
    const int row0 = t >> 2;            const int kk0 = (t & 3) * 8;
    const int row1 = (256 + t) >> 2;    const int kk1 = ((256 + t) & 3) * 8;

    const size_t aBase = (size_t)(by * 128);
    const size_t wBase = (size_t)(bx * 128);

    const ushort_t* ga0 = xb + (aBase + row0) * Kdim + kk0;
    const ushort_t* ga1 = xb + (aBase + row1) * Kdim + kk1;
    const ushort_t* gw0 = wb + (wBase + row0) * Kdim + kk0;
    const ushort_t* gw1 = wb + (wBase + row1) * Kdim + kk1;
    const ushort_t* gg0 = gb + (wBase + row0) * Kdim + kk0;
    const ushort_t* gg1 = gb + (wBase + row1) * Kdim + kk1;

    // LDS destination: wave-uniform base + lane*16B (hardware requirement)
    ushort_t* lA0 = As + (wave * 64) * 8;
    ushort_t* lA1 = As + (256 + wave * 64) * 8;
    ushort_t* lW0 = Ws + (wave * 64) * 8;
    ushort_t* lW1 = Ws + (256 + wave * 64) * 8;
    ushort_t* lG0 = Gs + (wave * 64) * 8;
    ushort_t* lG1 = Gs + (256 + wave * 64) * 8;

    const int fr = lane & 15;            // fragment row (m or n within 16-tile)
    const int kb = (lane >> 4) * 8;      // fragment k offset

    for (int k0 = 0; k0 < Kdim; k0 += 32) {
        __builtin_amdgcn_global_load_lds(GPTR(ga0 + k0), LPTR(lA0), 16, 0, 0);
        __builtin_amdgcn_global_load_lds(GPTR(ga1 + k0), LPTR(lA1), 16, 0, 0);
        __builtin_amdgcn_global_load_lds(GPTR(gw0 + k0), LPTR(lW0), 16, 0, 0);
        __builtin_amdgcn_global_load_lds(GPTR(gw1 + k0), LPTR(lW1), 16, 0, 0);
        __builtin_amdgcn_global_load_lds(GPTR(gg0 + k0), LPTR(lG0), 16, 0, 0);
        __builtin_amdgcn_global_load_lds(GPTR(gg1 + k0), LPTR(lG1), 16, 0, 0);
        __syncthreads();  // drains vmcnt before barrier

        short8 af[4], wf[4], gf[4];
#pragma unroll
        for (int mt = 0; mt < 4; ++mt)
            af[mt] = *(const short8*)(As + (wm + mt * 16 + fr) * 32 + kb);
#pragma unroll
        for (int nt = 0; nt < 4; ++nt) {
            wf[nt] = *(const short8*)(Ws + (wn + nt * 16 + fr) * 32 + kb);
            gf[nt] = *(const short8*)(Gs + (wn + nt * 16 + fr) * 32 + kb);
        }
#pragma unroll
        for (int mt = 0; mt < 4; ++mt)
#pragma unroll
            for (int nt = 0; nt < 4; ++nt) {
                accB[mt][nt] = __builtin_amdgcn_mfma_f32_16x16x32_bf16(
                    af[mt], wf[nt], accB[mt][nt], 0, 0, 0);
                accP[mt][nt] = __builtin_amdgcn_mfma_f32_16x16x32_bf16(
                    af[mt], gf[nt], accP[mt][nt], 0, 0, 0);
            }
        __syncthreads();
    }

    // --- epilogue: out = base + bias[n] - lr[m]*(pert + bgrad[n]) ---
    // C/D layout (verified m89): col = lane&15, row = (lane>>4)*4 + reg
    const int col  = lane & 15;
    const int quad = lane >> 4;
    const int gmb  = by * 128 + wm;
    const int gnb  = bx * 128 + wn;

    float lrv[4][4];
#pragma unroll
    for (int mt = 0; mt < 4; ++mt)
#pragma unroll
        for (int i = 0; i < 4; ++i)
            lrv[mt][i] = lr[gmb + mt * 16 + quad * 4 + i];

#pragma unroll
    for (int nt = 0; nt < 4; ++nt) {
        const int gn = gnb + nt * 16 + col;
        const float bn = bias[gn];
        const float bg = bgrad[gn];
#pragma unroll
        for (int mt = 0; mt < 4; ++mt) {
#pragma unroll
            for (int i = 0; i < 4; ++i) {
                const int gm = gmb + mt * 16 + quad * 4 + i;
                out[(size_t)gm * Ndim + gn] =
                    accB[mt][nt][i] + bn - lrv[mt][i] * (accP[mt][nt][i] + bg);
            }
        }
    }
}

extern "C" void kernel_launch(void* const* d_in, const int* in_sizes, int n_in,
                              void* d_out, int out_size, void* d_ws, size_t ws_size,
                              hipStream_t stream) {
    const float* x     = (const float*)d_in[0];  // [4096, 2048]
    const float* W     = (const float*)d_in[1];  // [2048, 2048]
    const float* bias  = (const float*)d_in[2];  // [2048]
    const float* G     = (const float*)d_in[3];  // [2048, 2048]
    const float* bgrad = (const float*)d_in[4];  // [2048]
    const float* lr    = (const float*)d_in[5];  // [4096]
    float* out = (float*)d_out;

    const int nX = 4096 * 2048;
    const int nW = 2048 * 2048;

    // ws layout: xb (16MB) | wb (8MB) | gb (8MB) = 33.5 MB total
    ushort_t* xb = (ushort_t*)d_ws;
    ushort_t* wb = xb + nX;
    ushort_t* gb = wb + nW;

    cvt_bf16_kernel<<<nX / 8 / 256, 256, 0, stream>>>(x, xb, nX);
    cvt_bf16_kernel<<<nW / 8 / 256, 256, 0, stream>>>(W, wb, nW);
    cvt_bf16_kernel<<<nW / 8 / 256, 256, 0, stream>>>(G, gb, nW);

    dim3 grid(16, 32);  // N tiles x M tiles = 512 blocks = 2/CU
    fused_gemm_kernel<<<grid, 256, 0, stream>>>(xb, wb, gb, bias, bgrad, lr, out);
}

// Round 2
// 179.878 us; speedup vs baseline: 1.0330x; 1.0330x over previous
//
#include <hip/hip_runtime.h>

// OptimizedLinear: out = x@W^T + bias - lr[:,None]*(x@G^T + bias_grad)
// B=4096, IN=OUT=2048, fp32 in/out. bf16 MFMA fused dual-accumulator GEMM.
// Round 2: XOR-swizzled LDS granules (kills the 4 cyc/read bank conflicts
// measured in round 1), single merged convert kernel, nontemporal C stores.

typedef unsigned short ushort_t;
typedef __attribute__((ext_vector_type(8))) short short8;       // 8 bf16 = 4 VGPR
typedef __attribute__((ext_vector_type(8))) unsigned short ushort8;
typedef __attribute__((ext_vector_type(4))) float f32x4;

#define GPTR(p) ((const __attribute__((address_space(1))) void*)(p))
#define LPTR(p) ((__attribute__((address_space(3))) void*)(p))

__device__ __forceinline__ unsigned short f2bf(float f) {
    union { float f; unsigned u; } c; c.f = f;
    unsigned u = c.u;
    // round-to-nearest-even
    unsigned r = (u + 0x7fffu + ((u >> 16) & 1u)) >> 16;
    return (unsigned short)r;
}

// One launch converts x (uX ushort8-units), W (uW), G (uW). Unit = 8 elems.
__global__ void cvt_all_kernel(const float* __restrict__ x,
                               const float* __restrict__ W,
                               const float* __restrict__ G,
                               ushort_t* __restrict__ xb,
                               ushort_t* __restrict__ wb,
                               ushort_t* __restrict__ gb,
                               int uX, int uW) {
    int u = blockIdx.x * blockDim.x + threadIdx.x;
    const float* src; ushort_t* dst;
    if (u < uX)            { src = x; dst = xb; }
    else if (u < uX + uW)  { src = W; dst = wb; u -= uX; }
    else                   { src = G; dst = gb; u -= uX + uW; }
    int i = u * 8;
    float4 a = *(const float4*)(src + i);
    float4 b = *(const float4*)(src + i + 4);
    ushort8 r;
    r[0] = f2bf(a.x); r[1] = f2bf(a.y); r[2] = f2bf(a.z); r[3] = f2bf(a.w);
    r[4] = f2bf(b.x); r[5] = f2bf(b.y); r[6] = f2bf(b.z); r[7] = f2bf(b.w);
    *(ushort8*)(dst + i) = r;
}

// ---- fused dual GEMM ----
// 128x128 C-tile per block (grid 16x32 = 512 = 2/CU), 256 threads = 4 waves,
// each wave 64x64 = 4x4 MFMA tiles, dual accumulators (base & pert).
// LDS tile layout: 512 granules of 16B. Granule for element-row r, k-granule q
// lives at slot r*4 + (q ^ (r&3))  [XOR swizzle -> conflict-free b128 reads].
static constexpr int Kdim = 2048;
static constexpr int Ndim = 2048;

__global__ __launch_bounds__(256, 2) void fused_gemm_kernel(
    const ushort_t* __restrict__ xb,   // [4096, 2048] bf16
    const ushort_t* __restrict__ wb,   // [2048, 2048] bf16
    const ushort_t* __restrict__ gb,   // [2048, 2048] bf16
    const float* __restrict__ bias,    // [2048]
    const float* __restrict__ bgrad,   // [2048]
    const float* __restrict__ lr,      // [4096]
    float* __restrict__ out)           // [4096, 2048] fp32
{
    __shared__ ushort_t As[128 * 32];
    __shared__ ushort_t Ws[128 * 32];
    __shared__ ushort_t Gs[128 * 32];

    const int t    = threadIdx.x;
    const int wave = t >> 6;
    const int lane = t & 63;
    const int wm   = (wave >> 1) * 64;
    const int wn   = (wave & 1) * 64;
    const int bx   = blockIdx.x;   // N tile (0..15)
    const int by   = blockIdx.y;   // M tile (0..31)

    f32x4 accB[4][4] = {};
    f32x4 accP[4][4] = {};

    // --- staging (global_load_lds width=16): LDS slot s = issue*256 + t.
    // Slot s holds tile granule (row = s>>2, q = (s&3) ^ ((s>>2)&3)); the
    // swizzle is applied on the GLOBAL fetch address (same 64B row -> same
    // coalescing), since the LDS dst is hardware-forced to base + lane*16.
    const int s0 = t,      row0 = s0 >> 2, kk0 = (((s0 & 3) ^ (row0 & 3)) * 8);
    const int s1 = 256 + t, row1 = s1 >> 2, kk1 = (((s1 & 3) ^ (row1 & 3)) * 8);

    const size_t aBase = (size_t)(by * 128);
    const size_t wBase = (size_t)(bx * 128);

    const ushort_t* ga0 = xb + (aBase + row0) * Kdim + kk0;
    const ushort_t* ga1 = xb + (aBase + row1) * Kdim + kk1;
    const ushort_t* gw0 = wb + (wBase + row0) * Kdim + kk0;
    const ushort_t* gw1 = wb + (wBase + row1) * Kdim + kk1;
    const ushort_t* gg0 = gb + (wBase + row0) * Kdim + kk0;
    const ushort_t* gg1 = gb + (wBase + row1) * Kdim + kk1;

    ushort_t* lA0 = As + (wave * 64) * 8;
    ushort_t* lA1 = As + (256 + wave * 64) * 8;
    ushort_t* lW0 = Ws + (wave * 64) * 8;
    ushort_t* lW1 = Ws + (256 + wave * 64) * 8;
    ushort_t* lG0 = Gs + (wave * 64) * 8;
    ushort_t* lG1 = Gs + (256 + wave * 64) * 8;

    const int fr = lane & 15;                         // fragment row
    const int kc = (((lane >> 4) ^ (fr & 3)) * 8);    // swizzled k-granule offset (elems)

    for (int k0 = 0; k0 < Kdim; k0 += 32) {
        __builtin_amdgcn_global_load_lds(GPTR(ga0 + k0), LPTR(lA0), 16, 0, 0);
        __builtin_amdgcn_global_load_lds(GPTR(ga1 + k0), LPTR(lA1), 16, 0, 0);
        __builtin_amdgcn_global_load_lds(GPTR(gw0 + k0), LPTR(lW0), 16, 0, 0);
        __builtin_amdgcn_global_load_lds(GPTR(gw1 + k0), LPTR(lW1), 16, 0, 0);
        __builtin_amdgcn_global_load_lds(GPTR(gg0 + k0), LPTR(lG0), 16, 0, 0);
        __builtin_amdgcn_global_load_lds(GPTR(gg1 + k0), LPTR(lG1), 16, 0, 0);
        __syncthreads();

        short8 af[4], wf[4], gf[4];
#pragma unroll
        for (int mt = 0; mt < 4; ++mt)
            af[mt] = *(const short8*)(As + (wm + mt * 16 + fr) * 32 + kc);
#pragma unroll
        for (int nt = 0; nt < 4; ++nt) {
            wf[nt] = *(const short8*)(Ws + (wn + nt * 16 + fr) * 32 + kc);
            gf[nt] = *(const short8*)(Gs + (wn + nt * 16 + fr) * 32 + kc);
        }
#pragma unroll
        for (int mt = 0; mt < 4; ++mt)
#pragma unroll
            for (int nt = 0; nt < 4; ++nt) {
                accB[mt][nt] = __builtin_amdgcn_mfma_f32_16x16x32_bf16(
                    af[mt], wf[nt], accB[mt][nt], 0, 0, 0);
                accP[mt][nt] = __builtin_amdgcn_mfma_f32_16x16x32_bf16(
                    af[mt], gf[nt], accP[mt][nt], 0, 0, 0);
            }
        __syncthreads();
    }

    // --- epilogue: out = base + bias[n] - lr[m]*(pert + bgrad[n]) ---
    // C/D layout: col = lane&15, row = (lane>>4)*4 + reg
    const int col  = lane & 15;
    const int quad = lane >> 4;
    const int gmb  = by * 128 + wm;
    const int gnb  = bx * 128 + wn;

    float lrv[4][4];
#pragma unroll
    for (int mt = 0; mt < 4; ++mt)
#pragma unroll
        for (int i = 0; i < 4; ++i)
            lrv[mt][i] = lr[gmb + mt * 16 + quad * 4 + i];

#pragma unroll
    for (int nt = 0; nt < 4; ++nt) {
        const int gn = gnb + nt * 16 + col;
        const float bn = bias[gn];
        const float bg = bgrad[gn];
#pragma unroll
        for (int mt = 0; mt < 4; ++mt) {
#pragma unroll
            for (int i = 0; i < 4; ++i) {
                const int gm = gmb + mt * 16 + quad * 4 + i;
                float v = accB[mt][nt][i] + bn - lrv[mt][i] * (accP[mt][nt][i] + bg);
                __builtin_nontemporal_store(v, out + (size_t)gm * Ndim + gn);
            }
        }
    }
}

extern "C" void kernel_launch(void* const* d_in, const int* in_sizes, int n_in,
                              void* d_out, int out_size, void* d_ws, size_t ws_size,
                              hipStream_t stream) {
    const float* x     = (const float*)d_in[0];  // [4096, 2048]
    const float* W     = (const float*)d_in[1];  // [2048, 2048]
    const float* bias  = (const float*)d_in[2];  // [2048]
    const float* G     = (const float*)d_in[3];  // [2048, 2048]
    const float* bgrad = (const float*)d_in[4];  // [2048]
    const float* lr    = (const float*)d_in[5];  // [4096]
    float* out = (float*)d_out;

    const int nX = 4096 * 2048;
    const int nW = 2048 * 2048;

    ushort_t* xb = (ushort_t*)d_ws;
    ushort_t* wb = xb + nX;
    ushort_t* gb = wb + nW;

    const int uX = nX / 8, uW = nW / 8;           // ushort8 units
    const int totalU = uX + 2 * uW;               // 2,097,152
    cvt_all_kernel<<<totalU / 256, 256, 0, stream>>>(x, W, G, xb, wb, gb, uX, uW);

    dim3 grid(16, 32);
    fused_gemm_kernel<<<grid, 256, 0, stream>>>(xb, wb, gb, bias, bgrad, lr, out);
}